// Round 11
// baseline (551.180 us; speedup 1.0000x reference)
//
#include <hip/hip_runtime.h>
#include <hip/hip_bf16.h>
#include <cmath>

#define T_STEPS 16
#define BATCH   512
#define N_IN    3072
#define S1      256
#define S2      256
#define S3      128
#define NEXP    8
#define M_ROWS  (T_STEPS * BATCH)   // 8192
#define MT_ALL  (M_ROWS / 32)       // 256 m-tiles

typedef int v4i  __attribute__((ext_vector_type(4)));
typedef int v16i __attribute__((ext_vector_type(16)));
typedef unsigned long long u64;
typedef unsigned int uint32;

// ---------------------------------------------------------------------------
// cast binary fp32 x -> i8 MFMA fragment tiles Af[kb][mt][lane16][16],
// m' = b*16 + t, k = kb*32 + (lane16>>5)*16 + byte.
// One thread per 16-B chunk: reads one aligned 64-B sector of x (16 floats),
// writes coalesced 16-B. Replaces the in-loop bit-unpack (R10: VALU 52% >
// MFMA 42% -- unpack was the co-bottleneck).
// ---------------------------------------------------------------------------
__global__ __launch_bounds__(256) void cast_x_frag(
    const float* __restrict__ x, char* __restrict__ Af)
{
    int t = blockIdx.x * 256 + threadIdx.x;   // chunks = 8192*3072/16
    int lane16 = t & 63;
    int mt = (t >> 6) & (MT_ALL - 1);
    int kb = t >> 14;                         // 0..95
    int mp = mt * 32 + (lane16 & 31);         // m' = b*16 + t
    int k0 = kb * 32 + (lane16 >> 5) * 16;
    int b  = mp >> 4;
    int tt = mp & 15;

    const float4* Xp = (const float4*)(x + ((size_t)tt * BATCH + b) * N_IN + k0);
    char out[16];
    #pragma unroll
    for (int f4 = 0; f4 < 4; ++f4) {
        float4 w = Xp[f4];
        out[f4 * 4 + 0] = (char)w.x;
        out[f4 * 4 + 1] = (char)w.y;
        out[f4 * 4 + 2] = (char)w.z;
        out[f4 * 4 + 3] = (char)w.w;
    }
    *(v4i*)(Af + (size_t)t * 16) = *(v4i*)out;
}

// ---------------------------------------------------------------------------
// Weight digitize -> MFMA fragment tiles. B-row gr = o*32 + e*4 + limb.
// Bf[kb][nt=o][lane16][16], lane16 = (e*4+limb) + 32*qd, k = kb*32+qd*16+byte.
// ---------------------------------------------------------------------------
template<int S, int K>
__global__ __launch_bounds__(256) void digitize_w_frag(
    const float* __restrict__ W, char* __restrict__ Bf)
{
    constexpr int LOGS = (S == 256) ? 8 : 7;
    int t = blockIdx.x * 256 + threadIdx.x;   // chunks = 2*S*K
    int lane16 = t & 63;
    int o  = (t >> 6) & (S - 1);
    int kb = t >> (6 + LOGS);
    int r  = lane16 & 31;
    int qd = lane16 >> 5;
    int e    = r >> 2;
    int limb = r & 3;
    int k0 = kb * 32 + qd * 16;

    const float4* Wp = (const float4*)(W + ((size_t)e * S + o) * K + k0);
    char out[16];
    #pragma unroll
    for (int f4 = 0; f4 < 4; ++f4) {
        float4 w = Wp[f4];
        float ws[4] = {w.x, w.y, w.z, w.w};
        #pragma unroll
        for (int c = 0; c < 4; ++c) {
            long long q = llrint((double)ws[c] * 4294967296.0);
            int d = 0;
            #pragma unroll
            for (int l = 0; l < 4; ++l) {
                int dl = (int)((q + 128) & 255) - 128;
                q = (q - dl) >> 8;
                if (l == limb) d = dl;
            }
            out[f4 * 4 + c] = (char)d;
        }
    }
    *(v4i*)(Bf + (size_t)t * 16) = *(v4i*)out;
}

// ---------------------------------------------------------------------------
// Fused expert-GEMM + limb recombine + LIF + gated combine + mean.
// Block 256(m') x 64(B-rows): 4 waves stacked in m share identical B
// addresses (L1 hits). Wave tile 64x64, 2x2 mfma_i32_32x32x32_i8.
// Both A and B are fragment tiles -> all hot loads are contiguous 1 KB.
// 3-slot rotating register prefetch (depth 2), fully unrolled K-loop.
// 1-D grid, XCD swizzle: xcd = id&7 owns one n-slab -> B L2-resident.
// ---------------------------------------------------------------------------
template<int K, int S, int SHIFT, bool WRITEC, int NBLK>
__global__ __launch_bounds__(256, 3) void fused_stage(
    const char* __restrict__ Ap, const char* __restrict__ Bf,
    const float* __restrict__ g, char* __restrict__ Cf,
    float* __restrict__ Mean)
{
    constexpr int KI = K / 64;
    constexpr int NT = S;                    // 32-row n-tiles in Bf
    constexpr int NS = NBLK / 8;
    __shared__ double hs[256][16];

    const int tid  = threadIdx.x;
    const int lane = tid & 63;
    const int w    = tid >> 6;
    const int col  = lane & 31;
    const int qd   = lane >> 5;
    const int wm   = w * 64;

    // XCD-swizzled block mapping: id = mblk*NBLK + inner*8 + xcd
    const int id   = blockIdx.x;
    const int nblk = (id & 7) * NS + ((id >> 3) % NS);
    const int mblk = id / NBLK;
    const int m0   = mblk * 256;

    const int nt0 = nblk * 2;
    const char* Bbase = Bf + ((size_t)nt0 * 64 + lane) * 16;
    const int mt0 = (m0 + wm) >> 5;
    const char* Abase = Ap + ((size_t)mt0 * 64 + lane) * 16;

    v16i acc[2][2];
    #pragma unroll
    for (int i = 0; i < 2; ++i)
        #pragma unroll
        for (int j = 0; j < 2; ++j)
            #pragma unroll
            for (int r = 0; r < 16; ++r) acc[i][j][r] = 0;

    auto loadB = [&](int kb, int jj) -> v4i {
        return *(const v4i*)(Bbase + ((size_t)kb * NT + jj) * 1024);
    };
    auto loadA = [&](int kb, int ii) -> v4i {
        return *(const v4i*)(Abase + ((size_t)kb * MT_ALL + ii) * 1024);
    };

    v4i Ab[3][4], Bb[3][4];
    #pragma unroll
    for (int s = 0; s < 2; ++s) {            // preload iters 0,1 -> slots 0,1
        #pragma unroll
        for (int ks = 0; ks < 2; ++ks) {
            Ab[s][ks * 2 + 0] = loadA(s * 2 + ks, 0);
            Ab[s][ks * 2 + 1] = loadA(s * 2 + ks, 1);
            Bb[s][ks * 2 + 0] = loadB(s * 2 + ks, 0);
            Bb[s][ks * 2 + 1] = loadB(s * 2 + ks, 1);
        }
    }

    #pragma unroll
    for (int it = 0; it < KI; ++it) {
        const int cur = it % 3;              // constant after full unroll
        const int pf  = (it + 2) % 3;
        const int itp = (it + 2 < KI) ? it + 2 : KI - 1;
        #pragma unroll
        for (int ks = 0; ks < 2; ++ks) {
            Ab[pf][ks * 2 + 0] = loadA(itp * 2 + ks, 0);
            Ab[pf][ks * 2 + 1] = loadA(itp * 2 + ks, 1);
            Bb[pf][ks * 2 + 0] = loadB(itp * 2 + ks, 0);
            Bb[pf][ks * 2 + 1] = loadB(itp * 2 + ks, 1);
        }
        #pragma unroll
        for (int ks = 0; ks < 2; ++ks) {
            acc[0][0] = __builtin_amdgcn_mfma_i32_32x32x32_i8(Ab[cur][ks*2+0], Bb[cur][ks*2+0], acc[0][0], 0,0,0);
            acc[0][1] = __builtin_amdgcn_mfma_i32_32x32x32_i8(Ab[cur][ks*2+0], Bb[cur][ks*2+1], acc[0][1], 0,0,0);
            acc[1][0] = __builtin_amdgcn_mfma_i32_32x32x32_i8(Ab[cur][ks*2+1], Bb[cur][ks*2+0], acc[1][0], 0,0,0);
            acc[1][1] = __builtin_amdgcn_mfma_i32_32x32x32_i8(Ab[cur][ks*2+1], Bb[cur][ks*2+1], acc[1][1], 0,0,0);
        }
    }

    // ---- limb recombine (exact, in double) -> LDS h tile ----
    const double sbase = 1.0 / (double)(1ll << SHIFT);
    const int limb = col & 3;
    const double lscale = (double)(1 << (8 * limb)) * sbase;
    #pragma unroll
    for (int j = 0; j < 2; ++j) {
        const int oe = j * 8 + (col >> 2);            // o_loc*8 + e
        #pragma unroll
        for (int i = 0; i < 2; ++i) {
            #pragma unroll
            for (int reg = 0; reg < 16; ++reg) {
                double d = (double)acc[i][j][reg] * lscale;
                d += __shfl_xor(d, 1);
                d += __shfl_xor(d, 2);
                if ((col & 3) == 0) {
                    int m = wm + i * 32 + (reg & 3) + 8 * (reg >> 2) + 4 * qd;
                    hs[m][oe] = d;
                }
            }
        }
    }
    __syncthreads();

    // ---- LIF scan: thread = (b_loc = tid>>4, o_loc = (tid>>3)&1, e = tid&7)
    const int b_loc  = tid >> 4;
    const int o_loc  = (tid >> 3) & 1;
    const int e      = tid & 7;
    const int oe     = o_loc * 8 + e;
    const float ge   = g[e];
    const int bg = mblk * 16 + b_loc;
    const int og = nblk * 2 + o_loc;

    // fragment-tile write coords for counts (k = og of this stage)
    const int kb_a   = og >> 5;
    const int qd_a   = (og >> 4) & 1;
    const int byte_a = og & 15;

    double v = 0.0;
    float gacc = 0.0f;
    #pragma unroll
    for (int t = 0; t < T_STEPS; ++t) {
        double h  = hs[b_loc * 16 + t][oe];
        double vv = v * 0.95 + h;
        int spk = (vv >= 1.0) ? 1 : 0;
        v = vv - (double)spk;
        float gs = ge * (float)spk;
        gs += __shfl_xor(gs, 1);
        gs += __shfl_xor(gs, 2);
        gs += __shfl_xor(gs, 4);
        gacc += gs;
        if (WRITEC) {
            int cnt = spk;
            cnt += __shfl_xor(cnt, 1);
            cnt += __shfl_xor(cnt, 2);
            cnt += __shfl_xor(cnt, 4);
            if (e == 0) {
                int mp = bg * 16 + t;
                int lane_a = (mp & 31) + 32 * qd_a;
                Cf[(((size_t)kb_a * MT_ALL + (mp >> 5)) * 64 + lane_a) * 16 + byte_a]
                    = (char)cnt;
            }
        }
    }
    if (e == 0) Mean[(size_t)bg * S + og] = gacc * 0.0625f;
}

// ---------------------------------------------------------------------------
// ws layout (bytes):
//   Af  @ 0          : 24 MB  (i8 x fragment tiles, 96 kb x 256 mt)
//   B1f @ 25165824   : 24 MB
//   B2f @ 50331648   :  2 MB
//   B3f @ 52428800   :  1 MB
//   c1f @ 53477376   :  2 MB  (frag-tile counts, K=256)
//   c2f @ 55574528   :  2 MB
// total ~57.7 MB
// ---------------------------------------------------------------------------
extern "C" void kernel_launch(void* const* d_in, const int* in_sizes, int n_in,
                              void* d_out, int out_size, void* d_ws, size_t ws_size,
                              hipStream_t stream) {
    const float* x  = (const float*)d_in[0];
    const float* W1 = (const float*)d_in[1];
    const float* W2 = (const float*)d_in[2];
    const float* W3 = (const float*)d_in[3];
    const float* g1 = (const float*)d_in[4];
    const float* g2 = (const float*)d_in[5];
    const float* g3 = (const float*)d_in[6];
    float* out = (float*)d_out;

    char* ws = (char*)d_ws;
    char* Af  = ws;
    char* B1f = ws + 25165824ull;
    char* B2f = ws + 50331648ull;
    char* B3f = ws + 52428800ull;
    char* c1f = ws + 53477376ull;
    char* c2f = ws + 55574528ull;

    dim3 blk(256);

    // --- precompute ---
    cast_x_frag<<<(M_ROWS * N_IN / 16) / 256, blk, 0, stream>>>(x, Af);
    digitize_w_frag<S1, N_IN><<<(2 * S1 * N_IN) / 256, blk, 0, stream>>>(W1, B1f);
    digitize_w_frag<S2, S1><<<(2 * S2 * S1) / 256, blk, 0, stream>>>(W2, B2f);
    digitize_w_frag<S3, S2><<<(2 * S3 * S2) / 256, blk, 0, stream>>>(W3, B3f);

    // --- three fused GEMM+LIF stages, XCD-swizzled 1-D grids ---
    fused_stage<N_IN, S1, 32, true,  128><<<32 * 128, blk, 0, stream>>>(
        Af, B1f, g1, c1f, out);
    fused_stage<S1,   S2, 35, true,  128><<<32 * 128, blk, 0, stream>>>(
        c1f, B2f, g2, c2f, out + BATCH * S1);
    fused_stage<S2,   S3, 35, false, 64><<<32 * 64, blk, 0, stream>>>(
        c2f, B3f, g3, nullptr, out + BATCH * (S1 + S2));
}